// Round 9
// baseline (1582.257 us; speedup 1.0000x reference)
//
#include <hip/hip_runtime.h>

typedef unsigned short u16;
typedef unsigned int u32;
typedef __attribute__((ext_vector_type(8))) __bf16 bf16x8;
typedef __attribute__((ext_vector_type(8))) short s16x8;
typedef __attribute__((ext_vector_type(4))) short s16x4;
typedef __attribute__((ext_vector_type(4))) float f32x4;

static __device__ __forceinline__ float bf2f(u16 h){
  union{u32 u; float f;} v; v.u = ((u32)h)<<16; return v.f;
}
static __device__ __forceinline__ u16 cvtbf(float f){
  return __builtin_bit_cast(u16, (__bf16)f);
}

#define GLD16(gp, lp) __builtin_amdgcn_global_load_lds(                      \
  (__attribute__((address_space(1))) void*)(void*)(gp),                      \
  (__attribute__((address_space(3))) void*)(void*)(lp), 16, 0, 0)

// ---------------------------------------------------------------------------
// K0: roll(-4,-4) + window partition + fp32->bf16 cast.  One wave per row.
// ---------------------------------------------------------------------------
__global__ __launch_bounds__(256)
void prep_x_kernel(const float* __restrict__ x, u16* __restrict__ xw)
{
  const int t = threadIdx.x, wv = t>>6, ln = t&63;
  const size_t row = (size_t)blockIdx.x*4 + wv;
  const int b = (int)(row>>12), wl = (int)((row>>6)&63), m = (int)(row&63);
  const int gh = ((wl>>3)*8 + (m>>3) + 4) & 63;
  const int gw = ((wl&7)*8 + (m&7) + 4) & 63;
  const size_t src = ((size_t)b*4096 + (size_t)gh*64 + gw)*512 + (size_t)ln*8;
  f32x4 a = *(const f32x4*)&x[src];
  f32x4 c = *(const f32x4*)&x[src+4];
  s16x8 o;
#pragma unroll
  for (int j=0;j<4;j++){ o[j] = (short)cvtbf(a[j]); o[j+4] = (short)cvtbf(c[j]); }
  *(s16x8*)&xw[row*512 + (size_t)ln*8] = o;
}

__global__ __launch_bounds__(256)
void cvt_bf16_kernel(const float* __restrict__ src, u16* __restrict__ dst, int n)
{
  const int i = (blockIdx.x*256 + threadIdx.x)*8;
  if (i >= n) return;
  f32x4 a = *(const f32x4*)&src[i];
  f32x4 c = *(const f32x4*)&src[i+4];
  s16x8 o;
#pragma unroll
  for (int j=0;j<4;j++){ o[j] = (short)cvtbf(a[j]); o[j+4] = (short)cvtbf(c[j]); }
  *(s16x8*)&dst[i] = o;
}

// ---------------------------------------------------------------------------
// CPB MLP table + bias expansion
// ---------------------------------------------------------------------------
static __device__ __forceinline__ float logcoord(int d){
  const float tt = (float)d * (8.0f/7.0f);
  const float sg = (tt > 0.f) ? 1.f : ((tt < 0.f) ? -1.f : 0.f);
  return sg * log2f(fabsf(tt) + 1.f) * (1.f/3.f);
}

__global__ __launch_bounds__(512)
void cpb_table_kernel(const float* __restrict__ w1, const float* __restrict__ b1,
                      const float* __restrict__ w2, float* __restrict__ table)
{
  __shared__ float hid[512];
  const int r = blockIdx.x, j = threadIdx.x;
  const float va = logcoord(r/15 - 7);
  const float vb = logcoord(r%15 - 7);
  hid[j] = fmaxf(va*w1[2*j] + vb*w1[2*j+1] + b1[j], 0.f);
  __syncthreads();
  if (j < 16){
    float acc = 0.f;
    for (int i=0;i<512;i++) acc += hid[i]*w2[j*512+i];
    table[r*16 + j] = acc;
  }
}

__global__ __launch_bounds__(256)
void bias_expand_kernel(const float* __restrict__ table, float* __restrict__ biasT)
{
  const int gid = blockIdx.x*256 + threadIdx.x;
  const int h = gid>>12, ij = gid&4095, i = ij>>6, j = ij&63;
  const int dr = (i>>3)-(j>>3)+7, dc = (i&7)-(j&7)+7;
  const float v = table[(dr*15+dc)*16 + h];
  biasT[gid] = 16.f / (1.f + __expf(-v));
}

// ---------------------------------------------------------------------------
// GEMM, 8-phase schedule (m201-style port).  C[M,N] = A[M,K]@B[N,K]^T.
// BM=BN=256, BK=64.  8 waves (2Mx4N), wave tile 128x64 -> acc[8][4].
// LDS 128KB: 2 dbuf x { A: 2 k-half planes (256rows x 32cols) | B: same }.
// Plane = 16KB, staged as one half-tile = 2 x global_load_lds(16B) issues.
// Iteration = 2 K-tiles (T=2it -> buf0 phases 0-3, T+1 -> buf1 phases 4-7).
// Phase q of a tile: ks=q>>1, mt-quad=(q&1)*4; reads {8,4,8,4}; 16 MFMA
// between two barriers with setprio(1) (T5 regime).
// Staging slots (verified disjoint from same/neighbor-phase reads; each
// phase's reads lgkm-complete before its closing barrier, so phase-p+1
// stages cannot race reads<=p):
//   p0: (T+1).k1 A+B -> buf1.k1   (buf1.k1 last read prev iter p7)
//   p2: (T+2).k0.A -> buf0        (buf0.k0 reads done after p1)
//   p3: (T+2).k0.B
//   p4: (T+2).k1 A+B -> buf0.k1   (buf0.k1 reads done after p3)
//   p6: (T+3).k0.A -> buf1        (buf1.k0 reads done after p5)
//   p7: (T+3).k0.B
// vmcnt(4) at END of p3 and p7 (before closing barrier -> cross-wave):
//   end-p3: outstanding<=2 halves (p2,p3) => p0 and prev p6,p7 landed
//           -> covers reads at p4..p7.
//   end-p7: outstanding<=2 halves (p6,p7) => p2,p3,p4 landed
//           -> covers reads at next p0..p3.
// T2 swizzle: chunk ^= (row>>1)&3 within 64B-row planes (2-way banks, free),
// applied on global SOURCE (gload_lds writes LDS linearly) and on ds_read.
// EPI: 0=qkv scatter(+q/v bias), 1=proj(+bias), 2=fc1(+bias+gelu), 3=fc2(+bias)
// ---------------------------------------------------------------------------
template<int EPI>
__global__ __launch_bounds__(512, 2)
void gemm8p(const u16* __restrict__ A, const u16* __restrict__ B,
            u16* __restrict__ Co, const float* __restrict__ bias0,
            const float* __restrict__ bias1, int N, int K)
{
  extern __shared__ u16 ls[];   // 2 x 32768 elems (buf) ; buf: A 2x8192 | B 2x8192
  const int t = threadIdx.x;
  const int wv = t>>6, ln = t&63;
  const int wr = wv>>2, wc = wv&3;
  const int lr = ln&15, lg = ln>>4;
  // XCD-chunked bijective swizzle (nwg % 8 == 0 for all our grids)
  const int gx = gridDim.x;
  const int lin = blockIdx.y*gx + blockIdx.x;
  const int q = (gx*(int)gridDim.y)>>3;
  const int lin2 = (lin&7)*q + (lin>>3);
  const int mT = lin2/gx, nT = lin2 - mT*gx;

  // staging addresses (per-lane global src carries the swizzle)
  const int cS = ((ln&3) ^ ((ln>>3)&3)) * 8;
  const u16* gA0 = A + (size_t)(mT*256 + wv*16 + (ln>>2))*K + cS;
  const u16* gB0 = B + (size_t)(nT*256 + wv*16 + (ln>>2))*K + cS;
  const size_t rstep = (size_t)128*K;

  // read offsets (plane-relative, same XOR involution)
  const int cR = (lg ^ ((lr>>1)&3))*8;
  const int rA = (wr*128 + lr)*32 + cR;          // + mt*512 ; + ks*8192 + d*32768
  const int rB = 16384 + (wc*64 + lr)*32 + cR;   // + nt*512

// stage one half-tile (tensor half: 256 rows x 32 cols) of tile tau, k-half kh
#define STG(gbase, tau, kh, isB) do {                                        \
    char* d_ = (char*)ls + (((tau)&1)*32768 + ((isB)?16384:0) + (kh)*8192 + wv*512)*2; \
    const u16* s_ = (gbase) + (size_t)(tau)*64 + (kh)*32;                    \
    GLD16(s_,         d_);                                                   \
    GLD16(s_ + rstep, d_ + 8192);                                            \
  } while(0)

  f32x4 acc[8][4] = {};
  bf16x8 bB[4];

#define PH(d, ks, BNEW, mtg, STAGES, VM) do {                                \
    const u16* la_ = ls + (d)*32768 + (ks)*8192;                             \
    bf16x8 aF0 = *(const bf16x8*)&la_[rA + ((mtg)+0)*512];                   \
    bf16x8 aF1 = *(const bf16x8*)&la_[rA + ((mtg)+1)*512];                   \
    bf16x8 aF2 = *(const bf16x8*)&la_[rA + ((mtg)+2)*512];                   \
    bf16x8 aF3 = *(const bf16x8*)&la_[rA + ((mtg)+3)*512];                   \
    if (BNEW) {                                                              \
      bB[0] = *(const bf16x8*)&la_[rB + 0*512];                              \
      bB[1] = *(const bf16x8*)&la_[rB + 1*512];                              \
      bB[2] = *(const bf16x8*)&la_[rB + 2*512];                              \
      bB[3] = *(const bf16x8*)&la_[rB + 3*512];                              \
    }                                                                        \
    STAGES;                                                                  \
    __builtin_amdgcn_s_barrier();                                            \
    __builtin_amdgcn_s_setprio(1);                                           \
    _Pragma("unroll")                                                        \
    for (int nt=0;nt<4;nt++)                                                 \
      acc[(mtg)+0][nt] = __builtin_amdgcn_mfma_f32_16x16x32_bf16(aF0, bB[nt], acc[(mtg)+0][nt], 0,0,0); \
    _Pragma("unroll")                                                        \
    for (int nt=0;nt<4;nt++)                                                 \
      acc[(mtg)+1][nt] = __builtin_amdgcn_mfma_f32_16x16x32_bf16(aF1, bB[nt], acc[(mtg)+1][nt], 0,0,0); \
    _Pragma("unroll")                                                        \
    for (int nt=0;nt<4;nt++)                                                 \
      acc[(mtg)+2][nt] = __builtin_amdgcn_mfma_f32_16x16x32_bf16(aF2, bB[nt], acc[(mtg)+2][nt], 0,0,0); \
    _Pragma("unroll")                                                        \
    for (int nt=0;nt<4;nt++)                                                 \
      acc[(mtg)+3][nt] = __builtin_amdgcn_mfma_f32_16x16x32_bf16(aF3, bB[nt], acc[(mtg)+3][nt], 0,0,0); \
    __builtin_amdgcn_s_setprio(0);                                           \
    if (VM) asm volatile("s_waitcnt vmcnt(4)" ::: "memory");                 \
    __builtin_amdgcn_s_barrier();                                            \
  } while(0)

  const int ntk = K>>6;      // K-tiles (BK=64); even for all our shapes
  const int niter = ntk>>1;  // 2 K-tiles per iteration
  // prologue: T0.k0, T0.k1, T1.k0 (12 loads, in this order)
  STG(gA0,0,0,0); STG(gB0,0,0,1);
  STG(gA0,0,1,0); STG(gB0,0,1,1);
  STG(gA0,1,0,0); STG(gB0,1,0,1);
  asm volatile("s_waitcnt vmcnt(4)" ::: "memory");   // T0 fully landed
  __builtin_amdgcn_s_barrier();

  for (int it=0; it<niter; ++it){
    const int T = 2*it;
    const bool s2 = (T+2) < ntk, s3 = (T+3) < ntk;
    PH(0,0,1,0, { STG(gA0,T+1,1,0); STG(gB0,T+1,1,1); }, 0);   // p0
    PH(0,0,0,4, {}, 0);                                         // p1
    PH(0,1,1,0, { if(s2) STG(gA0,T+2,0,0); }, 0);               // p2
    PH(0,1,0,4, { if(s2) STG(gB0,T+2,0,1); }, 1);               // p3 (+vmcnt)
    PH(1,0,1,0, { if(s2){ STG(gA0,T+2,1,0); STG(gB0,T+2,1,1);} }, 0); // p4
    PH(1,0,0,4, {}, 0);                                         // p5
    PH(1,1,1,0, { if(s3) STG(gA0,T+3,0,0); }, 0);               // p6
    PH(1,1,0,4, { if(s3) STG(gB0,T+3,0,1); }, 1);               // p7 (+vmcnt)
  }
#undef PH
#undef STG

  if (EPI == 0) {
    // qkv scatter: col -> (sec, head, d); dst[sec][win][head][tok][d]
    const int cb0 = nT*256 + wc*64;
    int secA[4], hhA[4], dA[4]; float bbA[4];
#pragma unroll
    for (int nt=0; nt<4; nt++) {
      const int cbp = cb0 + nt*16;
      secA[nt] = cbp >> 9;
      hhA[nt]  = (cbp >> 5) & 15;
      dA[nt]   = (cbp & 16) + lr;
      bbA[nt]  = (secA[nt]==1) ? 0.f : ((secA[nt]==0)?bias0:bias1)[(hhA[nt]<<5)+dA[nt]];
    }
#pragma unroll
    for (int mt=0; mt<8; mt++) {
      const int row = mT*256 + wr*128 + mt*16 + lg*4;
      const int win = row>>6, tok0 = row&63;
#pragma unroll
      for (int rr=0; rr<4; rr++) {
#pragma unroll
        for (int nt=0; nt<4; nt++) {
          u16* p = Co + (size_t)secA[nt]*67108864ULL + (size_t)win*32768
                      + hhA[nt]*2048 + (tok0+rr)*32 + dA[nt];
          *p = cvtbf(acc[mt][nt][rr] + bbA[nt]);
        }
      }
    }
  } else {
    const int c0 = nT*256 + wc*64;
    const int r0 = mT*256 + wr*128 + lg*4;
    float bbA[4];
#pragma unroll
    for (int nt=0; nt<4; nt++) bbA[nt] = bias0[c0 + nt*16 + lr];
#pragma unroll
    for (int mt=0; mt<8; mt++) {
#pragma unroll
      for (int rr=0; rr<4; rr++) {
        u16* pr = Co + (size_t)(r0 + mt*16 + rr)*N + c0 + lr;
#pragma unroll
        for (int nt=0; nt<4; nt++) {
          float v = acc[mt][nt][rr] + bbA[nt];
          if (EPI == 2) {
            const float z = 1.5957691216f * v * fmaf(0.044715f, v*v, 1.0f);
            v = v * __builtin_amdgcn_rcpf(1.0f + __expf(-z));
          }
          pr[nt*16] = cvtbf(v);
        }
      }
    }
  }
}

// ---------------------------------------------------------------------------
// Attention: one wave per (window, head).  Block = 4 windows x 1 head.
// qkv layout: [sec][win][head][tok][d]  (sec stride 67108864 elems)
// ---------------------------------------------------------------------------
__global__ __launch_bounds__(256)
void attn_win(const u16* __restrict__ qkv, const float* __restrict__ biasT,
              const float* __restrict__ logit_scale, u16* __restrict__ aout)
{
  __shared__ float sb[4096];
  __shared__ u16 sp[4][4096];
  __shared__ u16 svt[4][2048];
  const int t = threadIdx.x, wv = t>>6, ln = t&63;
  const int lr = ln&15, lg = ln>>4;
  const int head = blockIdx.y;
  for (int i = t; i < 4096; i += 256) sb[i] = biasT[head*4096 + i];
  __syncthreads();
  const int win = blockIdx.x*4 + wv;
  const size_t whi = (size_t)win*16 + head;
  const u16* qb = qkv + whi*2048;
  const u16* kb = qkv + 67108864ULL + whi*2048;
  const u16* vb = qkv + 134217728ULL + whi*2048;

  s16x8 qs[4], ks[4];
  float qin[4], kin[4];
#pragma unroll
  for (int mt=0;mt<4;mt++){
    qs[mt] = *(const s16x8*)&qb[(mt*16+lr)*32 + lg*8];
    float ss = 0.f;
#pragma unroll
    for (int j=0;j<8;j++){ float f = bf2f((u16)qs[mt][j]); ss += f*f; }
    ss += __shfl_xor(ss, 16); ss += __shfl_xor(ss, 32);
    qin[mt] = 1.f / fmaxf(sqrtf(ss), 1e-12f);
  }
#pragma unroll
  for (int nt=0;nt<4;nt++){
    ks[nt] = *(const s16x8*)&kb[(nt*16+lr)*32 + lg*8];
    float ss = 0.f;
#pragma unroll
    for (int j=0;j<8;j++){ float f = bf2f((u16)ks[nt][j]); ss += f*f; }
    ss += __shfl_xor(ss, 16); ss += __shfl_xor(ss, 32);
    kin[nt] = 1.f / fmaxf(sqrtf(ss), 1e-12f);
  }
  f32x4 S[4][4] = {};
#pragma unroll
  for (int mt=0;mt<4;mt++)
#pragma unroll
    for (int nt=0;nt<4;nt++)
      S[mt][nt] = __builtin_amdgcn_mfma_f32_16x16x32_bf16(
          __builtin_bit_cast(bf16x8, qs[mt]), __builtin_bit_cast(bf16x8, ks[nt]),
          S[mt][nt], 0,0,0);

  const float scale = expf(fminf(logit_scale[head], 4.6051702f));
  const int wl = win & 63, wh = wl>>3, ww = wl&7;
  float rsum[4][4];
#pragma unroll
  for (int mt=0;mt<4;mt++){
#pragma unroll
    for (int rr=0;rr<4;rr++){
      const int msub = lg*4 + rr;
      const float qn = __shfl(qin[mt], msub);
      const int m = mt*16 + msub;
      const int ridm = (wh==7 ? (((m>>3)<4) ? 3 : 6) : 0) + (ww==7 ? (((m&7)<4) ? 1 : 2) : 0);
#pragma unroll
      for (int nt=0;nt<4;nt++){
        const int n = nt*16 + lr;
        const int ridn = (wh==7 ? (((n>>3)<4) ? 3 : 6) : 0) + (ww==7 ? (((n&7)<4) ? 1 : 2) : 0);
        float v = S[mt][nt][rr] * (qn * kin[nt] * scale) + sb[m*64+n];
        if (ridm != ridn) v -= 100.f;
        S[mt][nt][rr] = v;
      }
      float mx = fmaxf(fmaxf(S[mt][0][rr], S[mt][1][rr]), fmaxf(S[mt][2][rr], S[mt][3][rr]));
      mx = fmaxf(mx, __shfl_xor(mx, 1)); mx = fmaxf(mx, __shfl_xor(mx, 2));
      mx = fmaxf(mx, __shfl_xor(mx, 4)); mx = fmaxf(mx, __shfl_xor(mx, 8));
      float sm = 0.f;
#pragma unroll
      for (int nt=0;nt<4;nt++){ float p = __expf(S[mt][nt][rr]-mx); S[mt][nt][rr] = p; sm += p; }
      sm += __shfl_xor(sm,1); sm += __shfl_xor(sm,2); sm += __shfl_xor(sm,4); sm += __shfl_xor(sm,8);
      rsum[mt][rr] = sm;
#pragma unroll
      for (int nt=0;nt<4;nt++){
        const int n = nt*16 + lr;
        sp[wv][(m*64 + n) ^ ((m&7)<<3)] = cvtbf(S[mt][nt][rr]);
      }
    }
  }
#pragma unroll
  for (int it=0; it<8; it++){
    const int flat = it*256 + ln*4;
    const int k = flat>>5, d0 = flat&31;
    s16x4 vv = *(const s16x4*)&vb[k*32 + d0];
#pragma unroll
    for (int e=0;e<4;e++)
      svt[wv][((d0+e)*64 + k) ^ (((d0+e)&7)<<3)] = (u16)vv[e];
  }
  f32x4 O[4][2] = {};
#pragma unroll
  for (int kk=0; kk<2; kk++){
    bf16x8 pf[4], vf[2];
#pragma unroll
    for (int mt=0;mt<4;mt++){
      const int am = mt*16 + lr;
      const int idx = (am*64 + kk*32 + lg*8) ^ ((am&7)<<3);
      s16x8 tmp; __builtin_memcpy(&tmp, (const char*)&sp[wv][0] + 2*idx, 16);
      pf[mt] = __builtin_bit_cast(bf16x8, tmp);
    }
#pragma unroll
    for (int n2=0;n2<2;n2++){
      const int vn = n2*16 + lr;
      const int idx = (vn*64 + kk*32 + lg*8) ^ ((vn&7)<<3);
      s16x8 tmp; __builtin_memcpy(&tmp, (const char*)&svt[wv][0] + 2*idx, 16);
      vf[n2] = __builtin_bit_cast(bf16x8, tmp);
    }
#pragma unroll
    for (int mt=0;mt<4;mt++)
#pragma unroll
      for (int n2=0;n2<2;n2++)
        O[mt][n2] = __builtin_amdgcn_mfma_f32_16x16x32_bf16(pf[mt], vf[n2], O[mt][n2], 0,0,0);
  }
  const size_t obase = (size_t)win*64;
#pragma unroll
  for (int mt=0;mt<4;mt++)
#pragma unroll
  for (int rr=0;rr<4;rr++){
    const int m = mt*16 + lg*4 + rr;
    const float inv = 1.f / rsum[mt][rr];
#pragma unroll
    for (int n2=0;n2<2;n2++){
      const int d = n2*16 + lr;
      aout[(obase + m)*512 + head*32 + d] = cvtbf(O[mt][n2][rr] * inv);
    }
  }
}

// ---------------------------------------------------------------------------
// K3b: window reverse + unshift + LN(norm1) + residual -> bf16 x1 only.
// ---------------------------------------------------------------------------
__global__ __launch_bounds__(256)
void scatter_ln_kernel(const u16* __restrict__ po, const float* __restrict__ x,
                       const float* __restrict__ w, const float* __restrict__ bb,
                       u16* __restrict__ x1b)
{
  const int t = threadIdx.x, wv = t>>6, ln = t&63;
  const size_t row = (size_t)blockIdx.x*4 + wv;
  s16x8 pv = *(const s16x8*)&po[row*512 + (size_t)ln*8];
  float v[8]; float s=0.f, s2=0.f;
#pragma unroll
  for (int j=0;j<8;j++){ v[j] = bf2f((u16)pv[j]); s += v[j]; s2 += v[j]*v[j]; }
#pragma unroll
  for (int d=1; d<64; d<<=1){ s += __shfl_xor(s,d); s2 += __shfl_xor(s2,d); }
  const float mu = s * 0.001953125f;
  const float var = s2 * 0.001953125f - mu*mu;
  const float rs = rsqrtf(var + 1e-5f);
  const int b = (int)(row>>12), wl = (int)((row>>6)&63), m = (int)(row&63);
  const int gh = ((wl>>3)*8 + (m>>3) + 4) & 63;
  const int gw = ((wl&7)*8 + (m&7) + 4) & 63;
  const size_t img = ((size_t)b*4096 + (size_t)gh*64 + gw)*512 + (size_t)ln*8;
  f32x4 xa = *(const f32x4*)&x[img];
  f32x4 xc = *(const f32x4*)&x[img+4];
  s16x8 ob;
  const int c0 = ln*8;
#pragma unroll
  for (int j=0;j<8;j++){
    const int c = c0 + j;
    const float lnv = (v[j]-mu)*rs*w[c] + bb[c];
    const float xx = (j<4) ? xa[j] : xc[j-4];
    ob[j] = (short)cvtbf(xx + lnv);
  }
  *(s16x8*)&x1b[img] = ob;
}

// ---------------------------------------------------------------------------
// K6: out = x1(bf16) + LN(y; norm2) -> fp32 d_out (full overwrite).
// ---------------------------------------------------------------------------
__global__ __launch_bounds__(256)
void final_ln_kernel(const u16* __restrict__ y, const u16* __restrict__ x1b,
                     const float* __restrict__ w, const float* __restrict__ bb,
                     float* __restrict__ out)
{
  const int t = threadIdx.x, wv = t>>6, ln = t&63;
  const size_t row = (size_t)blockIdx.x*4 + wv;
  const size_t idx = row*512 + (size_t)ln*8;
  s16x8 yv = *(const s16x8*)&y[idx];
  float v[8]; float s=0.f, s2=0.f;
#pragma unroll
  for (int j=0;j<8;j++){ v[j] = bf2f((u16)yv[j]); s += v[j]; s2 += v[j]*v[j]; }
#pragma unroll
  for (int d=1; d<64; d<<=1){ s += __shfl_xor(s,d); s2 += __shfl_xor(s2,d); }
  const float mu = s * 0.001953125f;
  const float var = s2 * 0.001953125f - mu*mu;
  const float rs = rsqrtf(var + 1e-5f);
  s16x8 xv = *(const s16x8*)&x1b[idx];
  f32x4 oa, oc;
  const int c0 = ln*8;
#pragma unroll
  for (int j=0;j<8;j++){
    const int c = c0 + j;
    const float lnv = (v[j]-mu)*rs*w[c] + bb[c];
    const float o = bf2f((u16)xv[j]) + lnv;
    if (j<4) oa[j] = o; else oc[j-4] = o;
  }
  *(f32x4*)&out[idx] = oa;
  *(f32x4*)&out[idx+4] = oc;
}

// ---------------------------------------------------------------------------
extern "C" void kernel_launch(void* const* d_in, const int* in_sizes, int n_in,
                              void* d_out, int out_size, void* d_ws, size_t ws_size,
                              hipStream_t stream)
{
  (void)in_sizes; (void)n_in; (void)out_size; (void)ws_size;
  const float* x        = (const float*)d_in[0];
  const float* qkv_w    = (const float*)d_in[1];
  const float* q_bias   = (const float*)d_in[2];
  const float* v_bias   = (const float*)d_in[3];
  const float* lscale   = (const float*)d_in[4];
  const float* cpb_w1   = (const float*)d_in[5];
  const float* cpb_b1   = (const float*)d_in[6];
  const float* cpb_w2   = (const float*)d_in[7];
  const float* proj_w   = (const float*)d_in[8];
  const float* proj_b   = (const float*)d_in[9];
  const float* n1w      = (const float*)d_in[10];
  const float* n1b      = (const float*)d_in[11];
  const float* n2w      = (const float*)d_in[12];
  const float* n2b      = (const float*)d_in[13];
  const float* fc1_w    = (const float*)d_in[14];
  const float* fc1_b    = (const float*)d_in[15];
  const float* fc2_w    = (const float*)d_in[16];
  const float* fc2_b    = (const float*)d_in[17];

  char* ws = (char*)d_ws;
  constexpr size_t XW_OFF   = 0;
  constexpr size_t ATT_OFF  = 134217728ULL;
  constexpr size_t PRJ_OFF  = 268435456ULL;
  constexpr size_t H_OFF    = 0;
  constexpr size_t BIAS_OFF = 536870912ULL;
  constexpr size_t TAB_OFF  = BIAS_OFF + 262144;
  constexpr size_t WQKV_OFF = TAB_OFF + 16384;
  constexpr size_t WPRJ_OFF = WQKV_OFF + 1572864;
  constexpr size_t WFC1_OFF = WPRJ_OFF + 524288;
  constexpr size_t WFC2_OFF = WFC1_OFF + 2097152;
  constexpr size_t QKV_OFF  = WFC2_OFF + 2097152;
  constexpr size_t X1B_OFF  = QKV_OFF;
  constexpr size_t Y_OFF    = QKV_OFF + 134217728ULL;

  u16*   xw    = (u16*)(ws + XW_OFF);
  u16*   attnO = (u16*)(ws + ATT_OFF);
  u16*   projO = (u16*)(ws + PRJ_OFF);
  u16*   hbuf  = (u16*)(ws + H_OFF);
  float* biasT = (float*)(ws + BIAS_OFF);
  float* table = (float*)(ws + TAB_OFF);
  u16*   wqkv  = (u16*)(ws + WQKV_OFF);
  u16*   wprj  = (u16*)(ws + WPRJ_OFF);
  u16*   wfc1  = (u16*)(ws + WFC1_OFF);
  u16*   wfc2  = (u16*)(ws + WFC2_OFF);
  u16*   qkvB  = (u16*)(ws + QKV_OFF);
  u16*   x1b   = (u16*)(ws + X1B_OFF);
  u16*   ybuf  = (u16*)(ws + Y_OFF);

  hipFuncSetAttribute((const void*)gemm8p<0>, hipFuncAttributeMaxDynamicSharedMemorySize, 131072);
  hipFuncSetAttribute((const void*)gemm8p<1>, hipFuncAttributeMaxDynamicSharedMemorySize, 131072);
  hipFuncSetAttribute((const void*)gemm8p<2>, hipFuncAttributeMaxDynamicSharedMemorySize, 131072);
  hipFuncSetAttribute((const void*)gemm8p<3>, hipFuncAttributeMaxDynamicSharedMemorySize, 131072);

  cvt_bf16_kernel<<<384, 256, 0, stream>>>(qkv_w, wqkv, 786432);
  cvt_bf16_kernel<<<128, 256, 0, stream>>>(proj_w, wprj, 262144);
  cvt_bf16_kernel<<<512, 256, 0, stream>>>(fc1_w, wfc1, 1048576);
  cvt_bf16_kernel<<<512, 256, 0, stream>>>(fc2_w, wfc2, 1048576);
  prep_x_kernel<<<32768, 256, 0, stream>>>(x, xw);
  cpb_table_kernel<<<225, 512, 0, stream>>>(cpb_w1, cpb_b1, cpb_w2, table);
  bias_expand_kernel<<<256, 256, 0, stream>>>(table, biasT);
  // qkv projection + scatter
  gemm8p<0><<<dim3(6,512), 512, 131072, stream>>>(xw, wqkv, qkvB, q_bias, v_bias, 1536, 512);
  // windowed cosine attention
  attn_win<<<dim3(512,16), 256, 0, stream>>>(qkvB, biasT, lscale, attnO);
  // output projection
  gemm8p<1><<<dim3(2,512), 512, 131072, stream>>>(attnO, wprj, projO, proj_b, nullptr, 512, 512);
  // window reverse + LN + residual (bf16 x1 only)
  scatter_ln_kernel<<<32768, 256, 0, stream>>>(projO, x, n1w, n1b, x1b);
  // MLP
  gemm8p<2><<<dim3(8,512), 512, 131072, stream>>>(x1b, wfc1, hbuf, fc1_b, nullptr, 2048, 512);
  gemm8p<3><<<dim3(2,512), 512, 131072, stream>>>(hbuf, wfc2, ybuf, fc2_b, nullptr, 512, 2048);
  // final LN + residual -> d_out
  final_ln_kernel<<<32768, 256, 0, stream>>>(ybuf, x1b, n2w, n2b, (float*)d_out);
}

// Round 10
// 1502.893 us; speedup vs baseline: 1.0528x; 1.0528x over previous
//
#include <hip/hip_runtime.h>

typedef unsigned short u16;
typedef unsigned int u32;
typedef __attribute__((ext_vector_type(8))) __bf16 bf16x8;
typedef __attribute__((ext_vector_type(8))) short s16x8;
typedef __attribute__((ext_vector_type(4))) short s16x4;
typedef __attribute__((ext_vector_type(4))) float f32x4;

static __device__ __forceinline__ float bf2f(u16 h){
  union{u32 u; float f;} v; v.u = ((u32)h)<<16; return v.f;
}
// hardware f32->bf16 (RNE) via compiler
static __device__ __forceinline__ u16 cvtbf(float f){
  return __builtin_bit_cast(u16, (__bf16)f);
}

#define GLD16(gp, lp) __builtin_amdgcn_global_load_lds(                      \
  (__attribute__((address_space(1))) void*)(void*)(gp),                      \
  (__attribute__((address_space(3))) void*)(void*)(lp), 16, 0, 0)

// ---------------------------------------------------------------------------
// K0 (fused preamble): blocks [0, 32768): roll(-4,-4) + window partition +
// fp32->bf16 cast of x (one wave per row).  Blocks [32768, 34304): the four
// weight casts fp32->bf16 (branch by block range; all segment sizes are
// exact multiples of 2048 elems/block).
// ---------------------------------------------------------------------------
__global__ __launch_bounds__(256)
void prep_fused(const float* __restrict__ x, u16* __restrict__ xw,
                const float* __restrict__ qkv_w, u16* __restrict__ wqkv,
                const float* __restrict__ proj_w, u16* __restrict__ wprj,
                const float* __restrict__ fc1_w, u16* __restrict__ wfc1,
                const float* __restrict__ fc2_w, u16* __restrict__ wfc2)
{
  const int t = threadIdx.x;
  int b = blockIdx.x;
  if (b < 32768) {
    const int wv = t>>6, ln = t&63;
    const size_t row = (size_t)b*4 + wv;
    const int bb = (int)(row>>12), wl = (int)((row>>6)&63), m = (int)(row&63);
    const int gh = ((wl>>3)*8 + (m>>3) + 4) & 63;
    const int gw = ((wl&7)*8 + (m&7) + 4) & 63;
    const size_t src = ((size_t)bb*4096 + (size_t)gh*64 + gw)*512 + (size_t)ln*8;
    f32x4 a = *(const f32x4*)&x[src];
    f32x4 c = *(const f32x4*)&x[src+4];
    s16x8 o;
#pragma unroll
    for (int j=0;j<4;j++){ o[j] = (short)cvtbf(a[j]); o[j+4] = (short)cvtbf(c[j]); }
    *(s16x8*)&xw[row*512 + (size_t)ln*8] = o;
  } else {
    b -= 32768;
    const float* src; u16* dst;
    if (b < 384)      { src = qkv_w;  dst = wqkv; }
    else if (b < 512) { src = proj_w; dst = wprj; b -= 384; }
    else if (b < 1024){ src = fc1_w;  dst = wfc1; b -= 512; }
    else              { src = fc2_w;  dst = wfc2; b -= 1024; }
    const int i = (b*256 + t)*8;
    f32x4 a = *(const f32x4*)&src[i];
    f32x4 c = *(const f32x4*)&src[i+4];
    s16x8 o;
#pragma unroll
    for (int j=0;j<4;j++){ o[j] = (short)cvtbf(a[j]); o[j+4] = (short)cvtbf(c[j]); }
    *(s16x8*)&dst[i] = o;
  }
}

// ---------------------------------------------------------------------------
// CPB MLP table + bias expansion
// ---------------------------------------------------------------------------
static __device__ __forceinline__ float logcoord(int d){
  const float tt = (float)d * (8.0f/7.0f);
  const float sg = (tt > 0.f) ? 1.f : ((tt < 0.f) ? -1.f : 0.f);
  return sg * log2f(fabsf(tt) + 1.f) * (1.f/3.f);
}

__global__ __launch_bounds__(512)
void cpb_table_kernel(const float* __restrict__ w1, const float* __restrict__ b1,
                      const float* __restrict__ w2, float* __restrict__ table)
{
  __shared__ float hid[512];
  const int r = blockIdx.x, j = threadIdx.x;
  const float va = logcoord(r/15 - 7);
  const float vb = logcoord(r%15 - 7);
  hid[j] = fmaxf(va*w1[2*j] + vb*w1[2*j+1] + b1[j], 0.f);
  __syncthreads();
  if (j < 16){
    float acc = 0.f;
    for (int i=0;i<512;i++) acc += hid[i]*w2[j*512+i];
    table[r*16 + j] = acc;
  }
}

__global__ __launch_bounds__(256)
void bias_expand_kernel(const float* __restrict__ table, float* __restrict__ biasT)
{
  const int gid = blockIdx.x*256 + threadIdx.x;
  const int h = gid>>12, ij = gid&4095, i = ij>>6, j = ij&63;
  const int dr = (i>>3)-(j>>3)+7, dc = (i&7)-(j&7)+7;
  const float v = table[(dr*15+dc)*16 + h];
  biasT[gid] = 16.f / (1.f + __expf(-v));
}

// ---------------------------------------------------------------------------
// GEMM: C[M,N] = A[M,K] @ B[N,K]^T (+epilogue).  128x256 tile, BK=32,
// 8 waves (2Mx4N), wave tile 64x64 (4x4 frags of 16x16x32 MFMA, 64 acc regs).
// ~116 unified regs -> 4 waves/SIMD; LDS = 3-buffer ring x 24KB = 72KB ->
// 2 blocks/CU co-resident (cross-block TLP hides barrier drains, m114).
// r4-r9 measured plateau: 705 TF +-3% across 6 schedule variants; 8-phase
// port (r9) regressed (-10%) -> this 2-barrier ring is the keeper.
// Ring depth 2, counted vmcnt:
//   iter t: vmcnt(3) ; barrier ; STAGE((t+2)%3) ; COMPUTE(t%3)
// Race-free mod 3: stage(t+2) issued after iter-t barrier; readers inside
// this barrier window touch buf t%3 (diff 2); in-flight writer (t+1) diff 1.
// T2: XOR-swizzle chunk^=((row>>1)&3) at 16B granularity, applied on global
// SOURCE (gload_lds writes LDS linearly) and on ds_read (same involution).
// Epilogue: rr outer / nt inner -> full 128B output lines per store burst.
// EPI: 0=qkv scatter(+q/v bias), 1=proj(+bias), 2=fc1(+bias+gelu), 3=fc2(+bias)
// ---------------------------------------------------------------------------
template<int EPI>
__global__ __launch_bounds__(512, 4)
void gemm128(const u16* __restrict__ A, const u16* __restrict__ B,
             u16* __restrict__ Co, const float* __restrict__ bias0,
             const float* __restrict__ bias1, int N, int K)
{
  extern __shared__ u16 ls[];   // 3 bufs x (A[128][32]=4096 u16 | B[256][32]=8192 u16)
  const int t = threadIdx.x;
  const int wv = t>>6, ln = t&63;
  const int wr = wv>>2, wc = wv&3;
  const int lr = ln&15, lg = ln>>4;
  // XCD-chunked bijective swizzle (nwg % 8 == 0 for all our grids)
  const int gx = gridDim.x;
  const int lin = blockIdx.y*gx + blockIdx.x;
  const int q = (gx*(int)gridDim.y)>>3;
  const int lin2 = (lin&7)*q + (lin>>3);
  const int mT = lin2/gx, nT = lin2 - mT*gx;

  // --- staging (per-lane global src carries the swizzle) ---
  const int rSub = ln>>2;
  const int cS = ((ln&3) ^ ((ln>>3)&3)) * 8;      // swizzled source chunk
  const u16* gA = A + (size_t)(mT*128 + wv*16 + rSub)*K + cS;
  const u16* gB = B + (size_t)(nT*256 + wv*16 + rSub)*K + cS;
  const size_t rstepB = (size_t)128*K;            // B load i=1: +128 rows
  char* lA = (char*)ls + wv*1024;                 // wave's linear LDS slot

  // --- read offsets (same XOR involution; 2-way max on banks = free) ---
  const int cR = (lg ^ ((lr>>1)&3))*8;
  const int offA0 = (wr*64 + lr)*32 + cR;         // + mt*512
  const int offB0 = (wc*64 + lr)*32 + cR;         // + nt*512

#define STAGE(buf, tt) do {                                                  \
    char* p_ = lA + (buf)*24576;                                             \
    const size_t ko_ = (size_t)(tt)*32;                                      \
    GLD16(gA + ko_,          p_);                                            \
    GLD16(gB + ko_,          p_ + 8192);                                     \
    GLD16(gB + ko_ + rstepB, p_ + 16384);                                    \
  } while(0)

  f32x4 acc[4][4] = {};

#define COMPUTE(buf) do {                                                    \
    const u16* la_ = ls + (buf)*12288;                                       \
    const u16* lb_ = la_ + 4096;                                             \
    bf16x8 bfr[4];                                                           \
    _Pragma("unroll")                                                        \
    for (int nt=0;nt<4;nt++) bfr[nt] = *(const bf16x8*)&lb_[offB0 + nt*512]; \
    _Pragma("unroll")                                                        \
    for (int mt=0;mt<4;mt++){                                                \
      bf16x8 af = *(const bf16x8*)&la_[offA0 + mt*512];                      \
      _Pragma("unroll")                                                      \
      for (int nt=0;nt<4;nt++)                                               \
        acc[mt][nt] = __builtin_amdgcn_mfma_f32_16x16x32_bf16(af, bfr[nt], acc[mt][nt], 0,0,0); \
    }                                                                        \
  } while(0)

  const int nsteps = K>>5;   // >= 16 for all our shapes
  STAGE(0,0); STAGE(1,1);
  int cb = 0;
  for (int t_=0; t_<nsteps-1; ++t_){
    asm volatile("s_waitcnt vmcnt(3)\n\ts_barrier" ::: "memory");
    if (t_+2 < nsteps){
      int sb = cb+2; if (sb>=3) sb-=3;
      STAGE(sb, t_+2);
    }
    COMPUTE(cb);
    cb = (cb==2)?0:cb+1;
  }
  asm volatile("s_waitcnt vmcnt(0)\n\ts_barrier" ::: "memory");
  COMPUTE(cb);
#undef STAGE
#undef COMPUTE

  if (EPI == 0) {
    // qkv scatter: col -> (sec, head, d); dst[sec][win][head][tok][d]
    const int cb0 = nT*256 + wc*64;
    int secA[4], hhA[4], dA[4]; float bbA[4];
#pragma unroll
    for (int nt=0; nt<4; nt++) {
      const int cbp = cb0 + nt*16;
      secA[nt] = cbp >> 9;
      hhA[nt]  = (cbp >> 5) & 15;
      dA[nt]   = (cbp & 16) + lr;
      bbA[nt]  = (secA[nt]==1) ? 0.f : ((secA[nt]==0)?bias0:bias1)[(hhA[nt]<<5)+dA[nt]];
    }
#pragma unroll
    for (int mt=0; mt<4; mt++) {
      const int row = mT*128 + wr*64 + mt*16 + lg*4;
      const int win = row>>6, tok0 = row&63;
#pragma unroll
      for (int rr=0; rr<4; rr++) {
#pragma unroll
        for (int nt=0; nt<4; nt++) {
          u16* p = Co + (size_t)secA[nt]*67108864ULL + (size_t)win*32768
                      + hhA[nt]*2048 + (tok0+rr)*32 + dA[nt];
          *p = cvtbf(acc[mt][nt][rr] + bbA[nt]);
        }
      }
    }
  } else {
    const int c0 = nT*256 + wc*64;
    const int r0 = mT*128 + wr*64 + lg*4;
    float bbA[4];
#pragma unroll
    for (int nt=0; nt<4; nt++) bbA[nt] = bias0[c0 + nt*16 + lr];
#pragma unroll
    for (int mt=0; mt<4; mt++) {
#pragma unroll
      for (int rr=0; rr<4; rr++) {
        u16* pr = Co + (size_t)(r0 + mt*16 + rr)*N + c0 + lr;
#pragma unroll
        for (int nt=0; nt<4; nt++) {
          float v = acc[mt][nt][rr] + bbA[nt];
          if (EPI == 2) {
            // tanh-form GELU: x * sigmoid(1.5957691*(x + 0.044715 x^3))
            const float z = 1.5957691216f * v * fmaf(0.044715f, v*v, 1.0f);
            v = v * __builtin_amdgcn_rcpf(1.0f + __expf(-z));
          }
          pr[nt*16] = cvtbf(v);
        }
      }
    }
  }
}

// ---------------------------------------------------------------------------
// Attention: one wave per (window, head).  Block = 4 windows x 1 head.
// qkv layout: [sec][win][head][tok][d]  (sec stride 67108864 elems)
// ---------------------------------------------------------------------------
__global__ __launch_bounds__(256)
void attn_win(const u16* __restrict__ qkv, const float* __restrict__ biasT,
              const float* __restrict__ logit_scale, u16* __restrict__ aout)
{
  __shared__ float sb[4096];
  __shared__ u16 sp[4][4096];
  __shared__ u16 svt[4][2048];
  const int t = threadIdx.x, wv = t>>6, ln = t&63;
  const int lr = ln&15, lg = ln>>4;
  const int head = blockIdx.y;
  for (int i = t; i < 4096; i += 256) sb[i] = biasT[head*4096 + i];
  __syncthreads();
  const int win = blockIdx.x*4 + wv;
  const size_t whi = (size_t)win*16 + head;
  const u16* qb = qkv + whi*2048;
  const u16* kb = qkv + 67108864ULL + whi*2048;
  const u16* vb = qkv + 134217728ULL + whi*2048;

  s16x8 qs[4], ks[4];
  float qin[4], kin[4];
#pragma unroll
  for (int mt=0;mt<4;mt++){
    qs[mt] = *(const s16x8*)&qb[(mt*16+lr)*32 + lg*8];
    float ss = 0.f;
#pragma unroll
    for (int j=0;j<8;j++){ float f = bf2f((u16)qs[mt][j]); ss += f*f; }
    ss += __shfl_xor(ss, 16); ss += __shfl_xor(ss, 32);
    qin[mt] = 1.f / fmaxf(sqrtf(ss), 1e-12f);
  }
#pragma unroll
  for (int nt=0;nt<4;nt++){
    ks[nt] = *(const s16x8*)&kb[(nt*16+lr)*32 + lg*8];
    float ss = 0.f;
#pragma unroll
    for (int j=0;j<8;j++){ float f = bf2f((u16)ks[nt][j]); ss += f*f; }
    ss += __shfl_xor(ss, 16); ss += __shfl_xor(ss, 32);
    kin[nt] = 1.f / fmaxf(sqrtf(ss), 1e-12f);
  }
  f32x4 S[4][4] = {};
#pragma unroll
  for (int mt=0;mt<4;mt++)
#pragma unroll
    for (int nt=0;nt<4;nt++)
      S[mt][nt] = __builtin_amdgcn_mfma_f32_16x16x32_bf16(
          __builtin_bit_cast(bf16x8, qs[mt]), __builtin_bit_cast(bf16x8, ks[nt]),
          S[mt][nt], 0,0,0);

  const float scale = expf(fminf(logit_scale[head], 4.6051702f));
  const int wl = win & 63, wh = wl>>3, ww = wl&7;
  float rsum[4][4];
#pragma unroll
  for (int mt=0;mt<4;mt++){
#pragma unroll
    for (int rr=0;rr<4;rr++){
      const int msub = lg*4 + rr;
      const float qn = __shfl(qin[mt], msub);
      const int m = mt*16 + msub;
      const int ridm = (wh==7 ? (((m>>3)<4) ? 3 : 6) : 0) + (ww==7 ? (((m&7)<4) ? 1 : 2) : 0);
#pragma unroll
      for (int nt=0;nt<4;nt++){
        const int n = nt*16 + lr;
        const int ridn = (wh==7 ? (((n>>3)<4) ? 3 : 6) : 0) + (ww==7 ? (((n&7)<4) ? 1 : 2) : 0);
        float v = S[mt][nt][rr] * (qn * kin[nt] * scale) + sb[m*64+n];
        if (ridm != ridn) v -= 100.f;
        S[mt][nt][rr] = v;
      }
      float mx = fmaxf(fmaxf(S[mt][0][rr], S[mt][1][rr]), fmaxf(S[mt][2][rr], S[mt][3][rr]));
      mx = fmaxf(mx, __shfl_xor(mx, 1)); mx = fmaxf(mx, __shfl_xor(mx, 2));
      mx = fmaxf(mx, __shfl_xor(mx, 4)); mx = fmaxf(mx, __shfl_xor(mx, 8));
      float sm = 0.f;
#pragma unroll
      for (int nt=0;nt<4;nt++){ float p = __expf(S[mt][nt][rr]-mx); S[mt][nt][rr] = p; sm += p; }
      sm += __shfl_xor(sm,1); sm += __shfl_xor(sm,2); sm += __shfl_xor(sm,4); sm += __shfl_xor(sm,8);
      rsum[mt][rr] = sm;
#pragma unroll
      for (int nt=0;nt<4;nt++){
        const int n = nt*16 + lr;
        sp[wv][(m*64 + n) ^ ((m&7)<<3)] = cvtbf(S[mt][nt][rr]);
      }
    }
  }
  // stage V^T (svt[d][k] = V[k][d]), XOR-swizzled rows
#pragma unroll
  for (int it=0; it<8; it++){
    const int flat = it*256 + ln*4;
    const int k = flat>>5, d0 = flat&31;
    s16x4 vv = *(const s16x4*)&vb[k*32 + d0];
#pragma unroll
    for (int e=0;e<4;e++)
      svt[wv][((d0+e)*64 + k) ^ (((d0+e)&7)<<3)] = (u16)vv[e];
  }
  // PV
  f32x4 O[4][2] = {};
#pragma unroll
  for (int kk=0; kk<2; kk++){
    bf16x8 pf[4], vf[2];
#pragma unroll
    for (int mt=0;mt<4;mt++){
      const int am = mt*16 + lr;
      const int idx = (am*64 + kk*32 + lg*8) ^ ((am&7)<<3);
      s16x8 tmp; __builtin_memcpy(&tmp, (const char*)&sp[wv][0] + 2*idx, 16);
      pf[mt] = __builtin_bit_cast(bf16x8, tmp);
    }
#pragma unroll
    for (int n2=0;n2<2;n2++){
      const int vn = n2*16 + lr;
      const int idx = (vn*64 + kk*32 + lg*8) ^ ((vn&7)<<3);
      s16x8 tmp; __builtin_memcpy(&tmp, (const char*)&svt[wv][0] + 2*idx, 16);
      vf[n2] = __builtin_bit_cast(bf16x8, tmp);
    }
#pragma unroll
    for (int mt=0;mt<4;mt++)
#pragma unroll
      for (int n2=0;n2<2;n2++)
        O[mt][n2] = __builtin_amdgcn_mfma_f32_16x16x32_bf16(pf[mt], vf[n2], O[mt][n2], 0,0,0);
  }
  const size_t obase = (size_t)win*64;
#pragma unroll
  for (int mt=0;mt<4;mt++)
#pragma unroll
  for (int rr=0;rr<4;rr++){
    const int m = mt*16 + lg*4 + rr;
    const float inv = 1.f / rsum[mt][rr];
#pragma unroll
    for (int n2=0;n2<2;n2++){
      const int d = n2*16 + lr;
      aout[(obase + m)*512 + head*32 + d] = cvtbf(O[mt][n2][rr] * inv);
    }
  }
}

// ---------------------------------------------------------------------------
// K3b: window reverse + unshift + LN(norm1) + residual -> bf16 x1 only.
// Residual read from xw (bf16, window order, coalesced): xw[row] is exactly
// bf16(x[img]) by construction in prep_fused (same img formula), so the
// fp32 image-order gather of x is unnecessary (saves 134MB + gather).
// ---------------------------------------------------------------------------
__global__ __launch_bounds__(256)
void scatter_ln_kernel(const u16* __restrict__ po, const u16* __restrict__ xw,
                       const float* __restrict__ w, const float* __restrict__ bb,
                       u16* __restrict__ x1b)
{
  const int t = threadIdx.x, wv = t>>6, ln = t&63;
  const size_t row = (size_t)blockIdx.x*4 + wv;
  s16x8 pv = *(const s16x8*)&po[row*512 + (size_t)ln*8];
  float v[8]; float s=0.f, s2=0.f;
#pragma unroll
  for (int j=0;j<8;j++){ v[j] = bf2f((u16)pv[j]); s += v[j]; s2 += v[j]*v[j]; }
#pragma unroll
  for (int d=1; d<64; d<<=1){ s += __shfl_xor(s,d); s2 += __shfl_xor(s2,d); }
  const float mu = s * 0.001953125f;
  const float var = s2 * 0.001953125f - mu*mu;
  const float rs = rsqrtf(var + 1e-5f);
  s16x8 xv = *(const s16x8*)&xw[row*512 + (size_t)ln*8];
  const int b = (int)(row>>12), wl = (int)((row>>6)&63), m = (int)(row&63);
  const int gh = ((wl>>3)*8 + (m>>3) + 4) & 63;
  const int gw = ((wl&7)*8 + (m&7) + 4) & 63;
  const size_t img = ((size_t)b*4096 + (size_t)gh*64 + gw)*512 + (size_t)ln*8;
  s16x8 ob;
  const int c0 = ln*8;
#pragma unroll
  for (int j=0;j<8;j++){
    const int c = c0 + j;
    const float lnv = (v[j]-mu)*rs*w[c] + bb[c];
    ob[j] = (short)cvtbf(bf2f((u16)xv[j]) + lnv);
  }
  *(s16x8*)&x1b[img] = ob;
}

// ---------------------------------------------------------------------------
// K6: out = x1(bf16) + LN(y; norm2) -> fp32 d_out (full overwrite).
// ---------------------------------------------------------------------------
__global__ __launch_bounds__(256)
void final_ln_kernel(const u16* __restrict__ y, const u16* __restrict__ x1b,
                     const float* __restrict__ w, const float* __restrict__ bb,
                     float* __restrict__ out)
{
  const int t = threadIdx.x, wv = t>>6, ln = t&63;
  const size_t row = (size_t)blockIdx.x*4 + wv;
  const size_t idx = row*512 + (size_t)ln*8;
  s16x8 yv = *(const s16x8*)&y[idx];
  float v[8]; float s=0.f, s2=0.f;
#pragma unroll
  for (int j=0;j<8;j++){ v[j] = bf2f((u16)yv[j]); s += v[j]; s2 += v[j]*v[j]; }
#pragma unroll
  for (int d=1; d<64; d<<=1){ s += __shfl_xor(s,d); s2 += __shfl_xor(s2,d); }
  const float mu = s * 0.001953125f;
  const float var = s2 * 0.001953125f - mu*mu;
  const float rs = rsqrtf(var + 1e-5f);
  s16x8 xv = *(const s16x8*)&x1b[idx];
  f32x4 oa, oc;
  const int c0 = ln*8;
#pragma unroll
  for (int j=0;j<8;j++){
    const int c = c0 + j;
    const float lnv = (v[j]-mu)*rs*w[c] + bb[c];
    const float o = bf2f((u16)xv[j]) + lnv;
    if (j<4) oa[j] = o; else oc[j-4] = o;
  }
  *(f32x4*)&out[idx] = oa;
  *(f32x4*)&out[idx+4] = oc;
}

// ---------------------------------------------------------------------------
extern "C" void kernel_launch(void* const* d_in, const int* in_sizes, int n_in,
                              void* d_out, int out_size, void* d_ws, size_t ws_size,
                              hipStream_t stream)
{
  (void)in_sizes; (void)n_in; (void)out_size; (void)ws_size;
  const float* x        = (const float*)d_in[0];
  const float* qkv_w    = (const float*)d_in[1];
  const float* q_bias   = (const float*)d_in[2];
  const float* v_bias   = (const float*)d_in[3];
  const float* lscale   = (const float*)d_in[4];
  const float* cpb_w1   = (const float*)d_in[5];
  const float* cpb_b1   = (const float*)d_in[6];
  const float* cpb_w2   = (const float*)d_in[7];
  const float* proj_w   = (const float*)d_in[8];
  const float* proj_b   = (const float*)d_in[9];
  const float* n1w      = (const float*)d_in[10];
  const float* n1b      = (const float*)d_in[11];
  const float* n2w      = (const float*)d_in[12];
  const float* n2b      = (const float*)d_in[13];
  const float* fc1_w    = (const float*)d_in[14];
  const float* fc1_b    = (const float*)d_in[15];
  const float* fc2_w    = (const float*)d_in[16];
  const float* fc2_b    = (const float*)d_in[17];

  char* ws = (char*)d_ws;
  constexpr size_t XW_OFF   = 0;                       // xw (dead after scatter_ln)
  constexpr size_t ATT_OFF  = 134217728ULL;
  constexpr size_t PRJ_OFF  = 268435456ULL;
  constexpr size_t H_OFF    = 0;                       // fc1 out (written after scatter_ln)
  constexpr size_t BIAS_OFF = 536870912ULL;
  constexpr size_t TAB_OFF  = BIAS_OFF + 262144;
  constexpr size_t WQKV_OFF = TAB_OFF + 16384;
  constexpr size_t WPRJ_OFF = WQKV_OFF + 1572864;
  constexpr size_t WFC1_OFF = WPRJ_OFF + 524288;
  constexpr size_t WFC2_OFF = WFC1_OFF + 2097152;
  constexpr size_t QKV_OFF  = WFC2_OFF + 2097152;
  constexpr size_t X1B_OFF  = QKV_OFF;
  constexpr size_t Y_OFF    = QKV_OFF + 134217728ULL;

  u16*   xw    = (u16*)(ws + XW_OFF);
  u16*   attnO = (u16*)(ws + ATT_OFF);
  u16*   projO = (u16*)(ws + PRJ_OFF);
  u16*   hbuf  = (u16*)(ws + H_OFF);
  float* biasT = (float*)(ws + BIAS_OFF);
  float* table = (float*)(ws + TAB_OFF);
  u16*   wqkv  = (u16*)(ws + WQKV_OFF);
  u16*   wprj  = (u16*)(ws + WPRJ_OFF);
  u16*   wfc1  = (u16*)(ws + WFC1_OFF);
  u16*   wfc2  = (u16*)(ws + WFC2_OFF);
  u16*   qkvB  = (u16*)(ws + QKV_OFF);
  u16*   x1b   = (u16*)(ws + X1B_OFF);
  u16*   ybuf  = (u16*)(ws + Y_OFF);

  // allow 72 KiB dynamic LDS on the GEMM kernels (idempotent, capture-safe)
  hipFuncSetAttribute((const void*)gemm128<0>, hipFuncAttributeMaxDynamicSharedMemorySize, 73728);
  hipFuncSetAttribute((const void*)gemm128<1>, hipFuncAttributeMaxDynamicSharedMemorySize, 73728);
  hipFuncSetAttribute((const void*)gemm128<2>, hipFuncAttributeMaxDynamicSharedMemorySize, 73728);
  hipFuncSetAttribute((const void*)gemm128<3>, hipFuncAttributeMaxDynamicSharedMemorySize, 73728);

  // fused preamble: x -> rolled/windowed bf16, plus all weight casts
  prep_fused<<<34304, 256, 0, stream>>>(x, xw, qkv_w, wqkv, proj_w, wprj,
                                        fc1_w, wfc1, fc2_w, wfc2);
  // relative position bias
  cpb_table_kernel<<<225, 512, 0, stream>>>(cpb_w1, cpb_b1, cpb_w2, table);
  bias_expand_kernel<<<256, 256, 0, stream>>>(table, biasT);
  // qkv projection + scatter
  gemm128<0><<<dim3(6,1024), 512, 73728, stream>>>(xw, wqkv, qkvB, q_bias, v_bias, 1536, 512);
  // windowed cosine attention
  attn_win<<<dim3(512,16), 256, 0, stream>>>(qkvB, biasT, lscale, attnO);
  // output projection
  gemm128<1><<<dim3(2,1024), 512, 73728, stream>>>(attnO, wprj, projO, proj_b, nullptr, 512, 512);
  // window reverse + LN + residual (reads xw for the residual; bf16 x1 only)
  scatter_ln_kernel<<<32768, 256, 0, stream>>>(projO, xw, n1w, n1b, x1b);
  // MLP
  gemm128<2><<<dim3(8,1024), 512, 73728, stream>>>(x1b, wfc1, hbuf, fc1_b, nullptr, 2048, 512);
  gemm128<3><<<dim3(2,1024), 512, 73728, stream>>>(hbuf, wfc2, ybuf, fc2_b, nullptr, 512, 2048);
  // final LN + residual -> d_out (fp32, full overwrite)
  final_ln_kernel<<<32768, 256, 0, stream>>>(ybuf, x1b, n2w, n2b, (float*)d_out);
}